// Round 4
// baseline (342.931 us; speedup 1.0000x reference)
//
#include <hip/hip_runtime.h>

#define B_ 8
#define C_ 192
#define N_ 13824     // 24^3
#define HEADS 6
#define HD 32
#define THREEC 576
#define CH 54        // attn_partial chunks (256 n2 each)

typedef unsigned short ushort_t;
typedef unsigned int uint_t;
typedef __attribute__((ext_vector_type(8))) short short8;
typedef __attribute__((ext_vector_type(4))) float f32x4;

__device__ __forceinline__ float bf2f(ushort_t u) {
  union { uint_t u; float f; } c; c.u = ((uint_t)u) << 16; return c.f;
}
__device__ __forceinline__ float lo_f(uint_t u) {
  union { uint_t u; float f; } c; c.u = u << 16; return c.f;
}
__device__ __forceinline__ float hi_f(uint_t u) {
  union { uint_t u; float f; } c; c.u = u & 0xffff0000u; return c.f;
}
__device__ __forceinline__ ushort_t f2bf(float f) {
  union { float f; uint_t u; } c; c.f = f;
  uint_t u = c.u;
  uint_t r = (u + 0x7fffu + ((u >> 16) & 1u)) >> 16;  // RNE (finite values)
  return (ushort_t)r;
}

// LDS row stride for bf16 MFMA tiles: 200 shorts = 100 dwords (100%32=4):
// fragment ds_read_b128 over 16 consecutive rows lands 2 lanes/bank-quad (free).
#define LROW 200

// ---------------------------------------------------------------------------
// K1: fused transpose + MFMA GEMM.
// qkv[b][o][n] = sum_c w[o][c]*x[b][c][n] + bias[o]  (w,x fp32; out bf16)
// Block owns n-tile of 128 and ALL 576 o (9 passes of BM=64) -> x read once.
// Bs staged via per-thread 8-c gather (conflict-free b128 writes); B-frags
// cached in 96 VGPRs across passes. As prefetched to regs per pass.
// grid (108, 8), block 256 (4 waves, 2x2), 2 blocks/CU.
// ---------------------------------------------------------------------------
__global__ __launch_bounds__(256, 2) void qkv_fused(
    const float* __restrict__ x, const float* __restrict__ w,
    const float* __restrict__ bias, ushort_t* __restrict__ qkv) {
  __shared__ ushort_t Bs[128 * LROW];  // [n][c]
  __shared__ ushort_t As[64 * LROW];   // [o][c]
  int t = threadIdx.x;
  int n0 = blockIdx.x * 128, b = blockIdx.y;
  int wid = t >> 6, lane = t & 63;
  int ln16 = lane & 15, q4 = lane >> 4;
  const float* xb = x + (size_t)b * C_ * N_;

  // ---- stage Bs: transpose+convert x [c][n] fp32 -> [n][c] bf16 ----
  {
    int nl = t & 127;
    int cb0 = (t >> 7) * 8;
#pragma unroll
    for (int it = 0; it < 12; ++it) {
      int cb = cb0 + it * 16;
      float v[8];
#pragma unroll
      for (int j = 0; j < 8; ++j)
        v[j] = xb[(size_t)(cb + j) * N_ + n0 + nl];
      union { ushort_t us[8]; uint4 u4; } pk;
#pragma unroll
      for (int j = 0; j < 8; ++j) pk.us[j] = f2bf(v[j]);
      *(uint4*)&Bs[nl * LROW + cb] = pk.u4;  // quad=(nl+cb/8)%8: conflict-free
    }
  }

  // ---- prefetch A pass 0 (w fp32 -> bf16 pack in regs) ----
  int ar = t >> 2, au0 = t & 3;
  uint4 apre[6];
#pragma unroll
  for (int j = 0; j < 6; ++j) {
    int u = au0 + 4 * j;
    const float* src = w + (size_t)ar * C_ + u * 8;
    float4 v0 = *(const float4*)src;
    float4 v1 = *(const float4*)(src + 4);
    union { ushort_t us[8]; uint4 u4; } pk;
    pk.us[0] = f2bf(v0.x); pk.us[1] = f2bf(v0.y); pk.us[2] = f2bf(v0.z); pk.us[3] = f2bf(v0.w);
    pk.us[4] = f2bf(v1.x); pk.us[5] = f2bf(v1.y); pk.us[6] = f2bf(v1.z); pk.us[7] = f2bf(v1.w);
    apre[j] = pk.u4;
  }

  __syncthreads();  // Bs visible everywhere

  // write As(0); concurrently (pre-sync2) read B-frags from Bs into regs
#pragma unroll
  for (int j = 0; j < 6; ++j)
    *(uint4*)&As[ar * LROW + (au0 + 4 * j) * 8] = apre[j];

  int ncol = (wid & 1) * 64, mrow = (wid >> 1) * 32;
  short8 bb[6][4];
#pragma unroll
  for (int kk = 0; kk < 6; ++kk)
#pragma unroll
    for (int ni = 0; ni < 4; ++ni)
      bb[kk][ni] = *(const short8*)&Bs[(ncol + ni * 16 + ln16) * LROW + kk * 32 + q4 * 8];

  __syncthreads();  // As(0) ready

  for (int p = 0; p < 9; ++p) {
    // prefetch A(p+1)
    if (p < 8) {
      int o0n = (p + 1) * 64;
#pragma unroll
      for (int j = 0; j < 6; ++j) {
        int u = au0 + 4 * j;
        const float* src = w + (size_t)(o0n + ar) * C_ + u * 8;
        float4 v0 = *(const float4*)src;
        float4 v1 = *(const float4*)(src + 4);
        union { ushort_t us[8]; uint4 u4; } pk;
        pk.us[0] = f2bf(v0.x); pk.us[1] = f2bf(v0.y); pk.us[2] = f2bf(v0.z); pk.us[3] = f2bf(v0.w);
        pk.us[4] = f2bf(v1.x); pk.us[5] = f2bf(v1.y); pk.us[6] = f2bf(v1.z); pk.us[7] = f2bf(v1.w);
        apre[j] = pk.u4;
      }
    }

    float brg[2][4];
#pragma unroll
    for (int mi = 0; mi < 2; ++mi)
#pragma unroll
      for (int r = 0; r < 4; ++r)
        brg[mi][r] = bias[p * 64 + mrow + mi * 16 + q4 * 4 + r];

    f32x4 acc[2][4];
#pragma unroll
    for (int mi = 0; mi < 2; ++mi)
#pragma unroll
      for (int ni = 0; ni < 4; ++ni) acc[mi][ni] = (f32x4){0.f, 0.f, 0.f, 0.f};

#pragma unroll
    for (int kk = 0; kk < 6; ++kk) {
      short8 a[2];
#pragma unroll
      for (int mi = 0; mi < 2; ++mi)
        a[mi] = *(const short8*)&As[(mrow + mi * 16 + ln16) * LROW + kk * 32 + q4 * 8];
#pragma unroll
      for (int mi = 0; mi < 2; ++mi)
#pragma unroll
        for (int ni = 0; ni < 4; ++ni)
          acc[mi][ni] = __builtin_amdgcn_mfma_f32_16x16x32_bf16(
              a[mi], bb[kk][ni], acc[mi][ni], 0, 0, 0);
    }

    // epilogue: +bias, bf16, pack n-pairs, b32 stores
#pragma unroll
    for (int mi = 0; mi < 2; ++mi)
#pragma unroll
      for (int ni = 0; ni < 4; ++ni)
#pragma unroll
        for (int r = 0; r < 4; ++r) {
          float v = acc[mi][ni][r] + brg[mi][r];
          uint_t bf = f2bf(v);
          uint_t pv = (uint_t)__shfl_xor((int)bf, 1);
          if (!(lane & 1)) {
            int o_l = p * 64 + mrow + mi * 16 + q4 * 4 + r;
            int n_l = ncol + ni * 16 + ln16;
            *(uint_t*)&qkv[(size_t)(b * THREEC + o_l) * N_ + n0 + n_l] =
                bf | (pv << 16);
          }
        }

    __syncthreads();  // all waves done reading As
    if (p < 8) {
#pragma unroll
      for (int j = 0; j < 6; ++j)
        *(uint4*)&As[ar * LROW + (au0 + 4 * j) * 8] = apre[j];
      __syncthreads();
    }
  }
}

// ---------------------------------------------------------------------------
// K2: per (b,chunk): for ALL heads, partial S[c][d]=sum q_c*k_d + norms.
// q,k rows are 768 B contiguous in scrambled qkv: [n2-row][q(192)|k(192)].
// 6 waves = 6 heads; 32-row ping-pong LDS staging (uint4). Each lane loops
// over every n2 row -> per-lane norm sums are complete (no reduction).
// grid (54, 8), block 384.
// ---------------------------------------------------------------------------
#define K2RS 392  // row stride shorts = 196 dw (196%32=4)
__global__ __launch_bounds__(384) void attn_partial(
    const ushort_t* __restrict__ qkv, float* __restrict__ Spart) {
  __shared__ ushort_t sh[2][32 * K2RS];
  int t = threadIdx.x;
  int chunk = blockIdx.x, b = blockIdx.y;
  const ushort_t* basep = qkv + (size_t)b * THREEC * N_;
  int n2base = chunk * 256;
  int h = t / 64, tl = t & 63;
  int c0 = (tl & 7) * 4, d0 = (tl >> 3) * 4;

  float acc[4][4];
#pragma unroll
  for (int i = 0; i < 4; ++i)
#pragma unroll
    for (int m = 0; m < 4; ++m) acc[i][m] = 0.f;
  float sqq[4] = {0.f, 0.f, 0.f, 0.f}, sqk[4] = {0.f, 0.f, 0.f, 0.f};

  uint4 pre[4];
  int srr[4], sru[4];
#pragma unroll
  for (int i = 0; i < 4; ++i) {
    int idx = t + i * 384;            // 1536 = 32 rows x 48 units
    srr[i] = idx / 48; sru[i] = idx - srr[i] * 48;
  }
  // load + write it=0
#pragma unroll
  for (int i = 0; i < 4; ++i) {
    int n2 = n2base + srr[i];
    int o = n2 / 24, rr = n2 - o * 24;
    pre[i] = *(const uint4*)(basep + (size_t)o * N_ + rr * THREEC + sru[i] * 8);
  }
#pragma unroll
  for (int i = 0; i < 4; ++i)
    *(uint4*)&sh[0][srr[i] * K2RS + sru[i] * 8] = pre[i];

  for (int it = 0; it < 8; ++it) {
    if (it < 7) {
#pragma unroll
      for (int i = 0; i < 4; ++i) {
        int n2 = n2base + (it + 1) * 32 + srr[i];
        int o = n2 / 24, rr = n2 - o * 24;
        pre[i] = *(const uint4*)(basep + (size_t)o * N_ + rr * THREEC + sru[i] * 8);
      }
    }
    __syncthreads();  // buf(it&1) visible; prior reads of buf((it+1)&1) done
    if (it < 7) {
#pragma unroll
      for (int i = 0; i < 4; ++i)
        *(uint4*)&sh[(it + 1) & 1][srr[i] * K2RS + sru[i] * 8] = pre[i];
    }
    const ushort_t* buf = sh[it & 1];
#pragma unroll 4
    for (int row = 0; row < 32; ++row) {
      uint2 qv = *(const uint2*)&buf[row * K2RS + h * HD + c0];
      uint2 kv = *(const uint2*)&buf[row * K2RS + C_ + h * HD + d0];
      float q[4] = {lo_f(qv.x), hi_f(qv.x), lo_f(qv.y), hi_f(qv.y)};
      float k[4] = {lo_f(kv.x), hi_f(kv.x), lo_f(kv.y), hi_f(kv.y)};
#pragma unroll
      for (int i = 0; i < 4; ++i) {
        sqq[i] = fmaf(q[i], q[i], sqq[i]);
        sqk[i] = fmaf(k[i], k[i], sqk[i]);
#pragma unroll
        for (int m = 0; m < 4; ++m)
          acc[i][m] = fmaf(q[i], k[m], acc[i][m]);
      }
    }
  }

  float* outp = Spart + ((size_t)(b * HEADS + h) * CH + chunk) * 1088;
#pragma unroll
  for (int i = 0; i < 4; ++i) {
    float4 v = {acc[i][0], acc[i][1], acc[i][2], acc[i][3]};
    *(float4*)&outp[(c0 + i) * 32 + d0] = v;
  }
  if (tl < 8) {                     // d0==0 lanes cover all c
#pragma unroll
    for (int i = 0; i < 4; ++i) outp[1024 + c0 + i] = sqq[i];
  }
  if ((tl & 7) == 0) {              // c0==0 lanes cover all d
#pragma unroll
    for (int i = 0; i < 4; ++i) outp[1056 + d0 + i] = sqk[i];
  }
}

// ---------------------------------------------------------------------------
// K3: reduce CH partials, softmax over d, then
// W2bf[b][co][h*32+d] = bf16( sum_c proj_w[co][c*6+h]*attn[c][d] ).
// grid (6, 8), block 256.
// ---------------------------------------------------------------------------
__global__ __launch_bounds__(256) void attn_final(
    const float* __restrict__ Spart, const float* __restrict__ temp,
    const float* __restrict__ proj_w, ushort_t* __restrict__ W2bf) {
  __shared__ float Sl[1024];
  __shared__ float invq[32], invk[32];
  __shared__ float Pl[192 * 33];
  int t = threadIdx.x;
  int h = blockIdx.x, b = blockIdx.y;
  const float* base = Spart + (size_t)(b * HEADS + h) * CH * 1088;

  for (int e = t; e < 1024; e += 256) {
    float s = 0.f;
    for (int ch = 0; ch < CH; ++ch) s += base[ch * 1088 + e];
    Sl[e] = s;
  }
  if (t < 64) {
    int jj = t & 31;
    int off = 1024 + (t >> 5) * 32 + jj;
    float s = 0.f;
    for (int ch = 0; ch < CH; ++ch) s += base[ch * 1088 + off];
    float inv = 1.f / fmaxf(sqrtf(s), 1e-12f);
    if (t < 32) invq[jj] = inv; else invk[jj] = inv;
  }
  for (int e = t; e < 6144; e += 256) {
    int co = e >> 5, c = e & 31;
    Pl[co * 33 + c] = proj_w[(size_t)co * C_ + c * HEADS + h];
  }
  __syncthreads();

  {
    int c = t >> 3, l8 = t & 7;
    float tmpv = temp[h];
    float iq = invq[c];
    float lg[4];
#pragma unroll
    for (int m = 0; m < 4; ++m) {
      int d = l8 * 4 + m;
      lg[m] = Sl[c * 32 + d] * iq * invk[d] * tmpv;
    }
    float mx = fmaxf(fmaxf(lg[0], lg[1]), fmaxf(lg[2], lg[3]));
    for (int off = 1; off < 8; off <<= 1) mx = fmaxf(mx, __shfl_xor(mx, off, 8));
    float ex[4]; float ssum = 0.f;
#pragma unroll
    for (int m = 0; m < 4; ++m) { ex[m] = __expf(lg[m] - mx); ssum += ex[m]; }
    for (int off = 1; off < 8; off <<= 1) ssum += __shfl_xor(ssum, off, 8);
    float inv = 1.f / ssum;
#pragma unroll
    for (int m = 0; m < 4; ++m) Sl[c * 32 + l8 * 4 + m] = ex[m] * inv;
  }
  __syncthreads();

  for (int e2 = t; e2 < 6144; e2 += 256) {
    int co = e2 >> 5, d = e2 & 31;
    float s = 0.f;
#pragma unroll
    for (int c = 0; c < 32; ++c)
      s = fmaf(Pl[co * 33 + c], Sl[c * 32 + d], s);
    W2bf[((size_t)b * C_ + co) * C_ + h * HD + d] = f2bf(s);
  }
}

// ---------------------------------------------------------------------------
// K4: fused MFMA GEMM y = W2 * V + proj_b. Block owns n2-tile of 128 and ALL
// 192 co (3 passes). V gathered from scrambled qkv (j-contiguous rows).
// grid (108, 8), block 256, 2 blocks/CU.
// ---------------------------------------------------------------------------
__global__ __launch_bounds__(256, 2) void proj_fused(
    const ushort_t* __restrict__ qkv, const ushort_t* __restrict__ W2bf,
    const float* __restrict__ pb, float* __restrict__ y) {
  __shared__ ushort_t Bs[128 * LROW];  // [n2][j]
  __shared__ ushort_t As[64 * LROW];   // [co][j]
  int t = threadIdx.x;
  int n2_0 = blockIdx.x * 128, b = blockIdx.y;
  int wid = t >> 6, lane = t & 63;
  int ln16 = lane & 15, q4 = lane >> 4;
  const ushort_t* basep = qkv + (size_t)b * THREEC * N_;

  // ---- stage Bs: V gather, b128 writes quad=(nl+u)%8 uniform ----
  {
    int nl = t >> 1, u0 = t & 1;
#pragma unroll
    for (int j = 0; j < 12; ++j) {
      int u = u0 + 2 * j;
      int n2 = n2_0 + nl;
      int o = n2 / 24, r2 = n2 - o * 24;
      uint4 v = *(const uint4*)(basep + (size_t)o * N_ + r2 * THREEC + 384 + u * 8);
      *(uint4*)&Bs[nl * LROW + u * 8] = v;
    }
  }

  // ---- prefetch A pass 0 (W2bf already bf16) ----
  int ar = t >> 2, au0 = t & 3;
  uint4 apre[6];
#pragma unroll
  for (int j = 0; j < 6; ++j) {
    int u = au0 + 4 * j;
    apre[j] = *(const uint4*)(W2bf + ((size_t)b * C_ + ar) * C_ + u * 8);
  }

  __syncthreads();

#pragma unroll
  for (int j = 0; j < 6; ++j)
    *(uint4*)&As[ar * LROW + (au0 + 4 * j) * 8] = apre[j];

  int ncol = (wid & 1) * 64, mrow = (wid >> 1) * 32;
  short8 bb[6][4];
#pragma unroll
  for (int kk = 0; kk < 6; ++kk)
#pragma unroll
    for (int ni = 0; ni < 4; ++ni)
      bb[kk][ni] = *(const short8*)&Bs[(ncol + ni * 16 + ln16) * LROW + kk * 32 + q4 * 8];

  __syncthreads();

  for (int p = 0; p < 3; ++p) {
    if (p < 2) {
      int o0n = (p + 1) * 64;
#pragma unroll
      for (int j = 0; j < 6; ++j) {
        int u = au0 + 4 * j;
        apre[j] = *(const uint4*)(W2bf + ((size_t)b * C_ + o0n + ar) * C_ + u * 8);
      }
    }

    float brg[2][4];
#pragma unroll
    for (int mi = 0; mi < 2; ++mi)
#pragma unroll
      for (int r = 0; r < 4; ++r)
        brg[mi][r] = pb[p * 64 + mrow + mi * 16 + q4 * 4 + r];

    f32x4 acc[2][4];
#pragma unroll
    for (int mi = 0; mi < 2; ++mi)
#pragma unroll
      for (int ni = 0; ni < 4; ++ni) acc[mi][ni] = (f32x4){0.f, 0.f, 0.f, 0.f};

#pragma unroll
    for (int kk = 0; kk < 6; ++kk) {
      short8 a[2];
#pragma unroll
      for (int mi = 0; mi < 2; ++mi)
        a[mi] = *(const short8*)&As[(mrow + mi * 16 + ln16) * LROW + kk * 32 + q4 * 8];
#pragma unroll
      for (int mi = 0; mi < 2; ++mi)
#pragma unroll
        for (int ni = 0; ni < 4; ++ni)
          acc[mi][ni] = __builtin_amdgcn_mfma_f32_16x16x32_bf16(
              a[mi], bb[kk][ni], acc[mi][ni], 0, 0, 0);
    }

#pragma unroll
    for (int mi = 0; mi < 2; ++mi)
#pragma unroll
      for (int ni = 0; ni < 4; ++ni)
#pragma unroll
        for (int r = 0; r < 4; ++r) {
          int co_l = p * 64 + mrow + mi * 16 + q4 * 4 + r;
          int n_l = ncol + ni * 16 + ln16;
          y[((size_t)b * C_ + co_l) * N_ + n2_0 + n_l] = acc[mi][ni][r] + brg[mi][r];
        }

    __syncthreads();
    if (p < 2) {
#pragma unroll
      for (int j = 0; j < 6; ++j)
        *(uint4*)&As[ar * LROW + (au0 + 4 * j) * 8] = apre[j];
      __syncthreads();
    }
  }
}

// ---------------------------------------------------------------------------
extern "C" void kernel_launch(void* const* d_in, const int* in_sizes, int n_in,
                              void* d_out, int out_size, void* d_ws, size_t ws_size,
                              hipStream_t stream) {
  const float* x      = (const float*)d_in[0];
  const float* qkv_w  = (const float*)d_in[1];
  const float* qkv_b  = (const float*)d_in[2];
  const float* temp   = (const float*)d_in[3];
  const float* proj_w = (const float*)d_in[4];
  const float* proj_b = (const float*)d_in[5];
  float* y = (float*)d_out;

  // ws: qkv bf16 127.4MB | Spart 11.3MB | W2bf 0.59MB
  char* wp = (char*)d_ws;
  ushort_t* qkv  = (ushort_t*)wp;  wp += (size_t)B_ * THREEC * N_ * 2;
  float* Spart   = (float*)wp;     wp += (size_t)B_ * HEADS * CH * 1088 * 4;
  ushort_t* W2bf = (ushort_t*)wp;

  qkv_fused<<<dim3(108, B_), 256, 0, stream>>>(x, qkv_w, qkv_b, qkv);
  attn_partial<<<dim3(CH, B_), 384, 0, stream>>>(qkv, Spart);
  attn_final<<<dim3(HEADS, B_), 256, 0, stream>>>(Spart, temp, proj_w, W2bf);
  proj_fused<<<dim3(108, B_), 256, 0, stream>>>(qkv, W2bf, proj_b, y);
}